// Round 4
// baseline (385.462 us; speedup 1.0000x reference)
//
#include <hip/hip_runtime.h>
#include <stdint.h>

#define NPIX 4096
#define CDIM 512

typedef _Float16 hv8 __attribute__((ext_vector_type(8)));
typedef float f32x4 __attribute__((ext_vector_type(4)));

__device__ __forceinline__ void lds_direct16(const _Float16* g, _Float16* l) {
    __builtin_amdgcn_global_load_lds(
        (const __attribute__((address_space(1))) void*)g,
        (__attribute__((address_space(3))) void*)l, 16, 0, 0);
}

// ---------------- weight fp32 -> fp16 ----------------
__global__ void cvt_w(const float* __restrict__ s0, const float* __restrict__ s1,
                      const float* __restrict__ s2, const float* __restrict__ s3,
                      _Float16* __restrict__ d0, _Float16* __restrict__ d1,
                      _Float16* __restrict__ d2, _Float16* __restrict__ d3) {
    int i = blockIdx.x * 256 + threadIdx.x;
    d0[i] = (_Float16)s0[i];
    d1[i] = (_Float16)s1[i];
    d2[i] = (_Float16)s2[i];
    d3[i] = (_Float16)s3[i];
}

// ---------------- groupnorm stats: one block per (b,g) ----------------
__global__ void stats_kernel(const float* __restrict__ x, float* __restrict__ stats) {
    int idx = blockIdx.x;
    const float4* base = (const float4*)(x + (long)idx * 16 * NPIX);
    int tid = threadIdx.x;
    float s = 0.f, sq = 0.f;
    for (int it = 0; it < 64; ++it) {
        float4 f = base[it * 256 + tid];
        s  += f.x + f.y + f.z + f.w;
        sq += f.x * f.x + f.y * f.y + f.z * f.z + f.w * f.w;
    }
    __shared__ float rs[256], rq[256];
    rs[tid] = s; rq[tid] = sq;
    __syncthreads();
    for (int st = 128; st > 0; st >>= 1) {
        if (tid < st) { rs[tid] += rs[tid + st]; rq[tid] += rq[tid + st]; }
        __syncthreads();
    }
    if (tid == 0) {
        float mean = rs[0] * (1.0f / 65536.0f);
        float var  = rq[0] * (1.0f / 65536.0f) - mean * mean;
        stats[idx * 2]     = mean;
        stats[idx * 2 + 1] = rsqrtf(var + 1e-6f);
    }
}

// ---------------- normalize + transpose: hT[b][n][c] = GN(x)[b][c][n] ----------------
__global__ void normT_kernel(const float* __restrict__ x, const float* __restrict__ stats,
                             const float* __restrict__ gamma, const float* __restrict__ beta,
                             _Float16* __restrict__ hT) {
    int b = blockIdx.z, c0 = blockIdx.x * 32, n0 = blockIdx.y * 32;
    int tid = threadIdx.x;
    __shared__ float t[32][33];
    int cl = tid >> 5;
    int nl = tid & 31;
    for (int r = 0; r < 4; ++r)
        t[r * 8 + cl][nl] = x[(long)b * CDIM * NPIX + (long)(c0 + r * 8 + cl) * NPIX + n0 + nl];
    __syncthreads();
    for (int r = 0; r < 4; ++r) {
        int nr = r * 8 + cl;
        int c = c0 + nl;
        float m    = stats[(b * 32 + (c >> 4)) * 2];
        float rstd = stats[(b * 32 + (c >> 4)) * 2 + 1];
        float val = (t[nl][nr] - m) * rstd * gamma[c] + beta[c];
        hT[(long)b * NPIX * CDIM + (long)(n0 + nr) * CDIM + c] = (_Float16)val;
    }
}

// ---------------- bt-form GEMM: D[M][N] = A[M][K] * BT[N][K]^T ----------------
template<int EPI>
__launch_bounds__(256, 2)
__global__ void gemm_bt_kernel(const _Float16* __restrict__ A, const _Float16* __restrict__ BT,
                               void* __restrict__ D, const float* __restrict__ bias,
                               const float* __restrict__ resid,
                               int M, int N, int K,
                               long aBatch, long bBatch, long dBatch, long rBatch) {
    const int b = blockIdx.z;
    A  += (long)b * aBatch;
    BT += (long)b * bBatch;
    const int m0 = blockIdx.y * 128;
    const int n0 = blockIdx.x * 128;
    const int tid = threadIdx.x;
    const int l = tid & 63;
    const int w = tid >> 6;
    const int wm = (w >> 1) * 64;
    const int wn = (w & 1) * 64;
    const int lr = l & 15;
    const int lk = l >> 4;
    __shared__ __align__(16) _Float16 As[128 * 32];
    __shared__ __align__(16) _Float16 Bs[128 * 32];
    f32x4 acc[4][4] = {};
    const int nK = K >> 5;
    for (int kt = 0; kt < nK; ++kt) {
        const int kb = kt * 32;
#pragma unroll
        for (int c = 0; c < 2; ++c) {
            int chunk = c * 256 + tid;
            int row = chunk >> 2;
            int k8 = (chunk & 3) * 8;
            _Float16* ldsA = As + (size_t)(c * 256 + (tid & ~63)) * 8;
            _Float16* ldsB = Bs + (size_t)(c * 256 + (tid & ~63)) * 8;
            lds_direct16(A  + (long)(m0 + row) * K + kb + k8, ldsA);
            lds_direct16(BT + (long)(n0 + row) * K + kb + k8, ldsB);
        }
        __syncthreads();
        hv8 af[4], bfr[4];
#pragma unroll
        for (int mi = 0; mi < 4; ++mi)
            af[mi] = *(const hv8*)(As + (size_t)(wm + mi * 16 + lr) * 32 + lk * 8);
#pragma unroll
        for (int ni = 0; ni < 4; ++ni)
            bfr[ni] = *(const hv8*)(Bs + (size_t)(wn + ni * 16 + lr) * 32 + lk * 8);
#pragma unroll
        for (int mi = 0; mi < 4; ++mi)
#pragma unroll
            for (int ni = 0; ni < 4; ++ni)
                acc[mi][ni] = __builtin_amdgcn_mfma_f32_16x16x32_f16(af[mi], bfr[ni], acc[mi][ni], 0, 0, 0);
        __syncthreads();
    }
#pragma unroll
    for (int mi = 0; mi < 4; ++mi)
#pragma unroll
        for (int ni = 0; ni < 4; ++ni)
#pragma unroll
            for (int r = 0; r < 4; ++r) {
                int row = m0 + wm + mi * 16 + lk * 4 + r;
                int col = n0 + wn + ni * 16 + lr;
                float val = acc[mi][ni][r];
                if (EPI == 0) {
                    ((_Float16*)D)[(long)b * dBatch + (long)row * N + col] = (_Float16)(val + bias[col]);
                } else if (EPI == 1) {
                    ((_Float16*)D)[(long)b * dBatch + (long)row * N + col] = (_Float16)(val + bias[row]);
                } else {
                    long idx = (long)row * N + col;
                    ((float*)D)[(long)b * dBatch + idx] =
                        val + bias[row] + resid[(long)b * rBatch + idx];
                }
            }
}

// ---------------- flash attention v4: i-tile 64, j-tile 32, j-split 2 ----------------
// Grid 256 linear. Decode pins each (batch, jhalf) combination to 2 XCDs so the
// K/V half (2+2 MB) is L2-resident. Each block: 64 q-rows, j-range 2048 (32-row
// K tiles x 64 steps). Partial per-half normalized O (fp16) + row-sums l (f32);
// combine_kernel merges the two halves.
__launch_bounds__(512, 2)
__global__ void attn_kernel(const _Float16* __restrict__ qT, const _Float16* __restrict__ kT,
                            const _Float16* __restrict__ v,
                            _Float16* __restrict__ p0, _Float16* __restrict__ p1,
                            float* __restrict__ lbuf) {
    __shared__ __align__(16) _Float16 Ks[2][32 * 512];   // 64 KB, XOR-swizzled rows
    __shared__ __align__(16) _Float16 ps[64 * 32];       // 4 KB, XOR-swizzled (64B rows)
    __shared__ float red[8][64];
    __shared__ float redt[64];

    const int g = blockIdx.x;
    const int xcd = g & 7;
    const int comb = xcd >> 1;                  // 0..3 -> (batch, jhalf)
    const int itile = ((g >> 3) << 1) | (xcd & 1);
    const int batch = comb >> 1;
    const int jhalf = comb & 1;
    const int i0 = itile * 64;
    const int jbase = jhalf * 2048;

    const int tid = threadIdx.x;
    const int l = tid & 63, w = tid >> 6;
    const int lr = l & 15, lk = l >> 4;
    const int iq = w >> 1, jq = w & 1;          // QK: S[64][32] -> wave quadrant
    const int ro = w & 3,  co = w >> 2;         // PV: O rows ro*16, c-range co*256

    const _Float16* qb = qT + (long)batch * NPIX * CDIM;
    const _Float16* kb = kT + (long)batch * NPIX * CDIM;
    const _Float16* vb = v  + (long)batch * CDIM * NPIX;

    // Q fragments in registers: rows i0 + iq*16 + lr, 16 k-chunks (64 VGPR)
    hv8 af[16];
    {
        const _Float16* qr = qb + (long)(i0 + iq * 16 + lr) * CDIM + lk * 8;
#pragma unroll
        for (int kk = 0; kk < 16; ++kk)
            af[kk] = *(const hv8*)(qr + kk * 32);
    }

    f32x4 oacc[16] = {};    // O rows ro*16+lk*4+r, cols co*256+ni*16+lr (64 VGPR)
    float lsum[4] = {};
    hv8 vf[16];

    // prologue: stage K tile 0 (rows w*4+q)
    {
        const _Float16* kp = kb + (long)(jbase + w * 4) * CDIM;
#pragma unroll
        for (int q = 0; q < 4; ++q) {
            int row = w * 4 + q;
            int cc = l ^ (row & 7);
            lds_direct16(kp + (long)q * CDIM + cc * 8, &Ks[0][row * 512]);
        }
    }
    __syncthreads();

    const float scale = 0.044194173824159216f;   // 1/sqrt(512)
    const _Float16* vlane  = vb + (long)(co * 256 + lr) * NPIX + jbase + lk * 8;
    const _Float16* kstage = kb + (long)(jbase + 32 + w * 4) * CDIM;

    for (int jt = 0; jt < 64; ++jt) {
        _Float16* kcur = Ks[jt & 1];
        _Float16* knxt = Ks[(jt + 1) & 1];

        // ---- (1) V fragments for THIS step (issued first) ----
#pragma unroll
        for (int ni = 0; ni < 16; ++ni)
            vf[ni] = *(const hv8*)(vlane + (long)ni * (16 * NPIX));
        __builtin_amdgcn_sched_barrier(0);

        // ---- (2) K staging for NEXT step (stays in flight past mid-barrier) ----
        if (jt < 63) {
#pragma unroll
            for (int q = 0; q < 4; ++q) {
                int row = w * 4 + q;
                int cc = l ^ (row & 7);
                lds_direct16(kstage + (long)q * CDIM + cc * 8, &knxt[row * 512]);
            }
        }
        __builtin_amdgcn_sched_barrier(0);

        // ---- (3) QK: 16x16 quadrant (rows iq*16, cols jq*16) ----
        f32x4 s = {};
        {
            const char* kbase = (const char*)kcur;
            const int j = jq * 16 + lr;
            const uint32_t sw = (uint32_t)((j & 7) << 4);
#pragma unroll
            for (int kk = 0; kk < 16; ++kk) {
                uint32_t off = ((uint32_t)(j * 1024 + kk * 64 + lk * 16)) ^ sw;
                hv8 bf = *(const hv8*)(kbase + off);
                s = __builtin_amdgcn_mfma_f32_16x16x32_f16(af[kk], bf, s, 0, 0, 0);
            }
        }

        // ---- (4) exp + ps write (swizzled, 64B rows) ----
#pragma unroll
        for (int r = 0; r < 4; ++r) {
            float p = __expf(s[r] * scale);
            lsum[r] += p;
            int i = iq * 16 + lk * 4 + r;
            int j = jq * 16 + lr;
            uint32_t off = ((uint32_t)(i * 64 + j * 2)) ^ ((uint32_t)((i & 7) << 4));
            *(_Float16*)((char*)ps + off) = (_Float16)p;
        }

        // ---- (5) mid barrier: drain LDS only; K staging stays outstanding ----
        asm volatile("s_waitcnt lgkmcnt(0)" ::: "memory");
        __builtin_amdgcn_sched_barrier(0);
        __builtin_amdgcn_s_barrier();

        // ---- (6) PV: O rows ro*16 x cols co*256 += P * V ----
        hv8 pa;
        {
            int row = ro * 16 + lr;
            uint32_t off = ((uint32_t)(row * 64 + lk * 16)) ^ ((uint32_t)((row & 7) << 4));
            pa = *(const hv8*)((const char*)ps + off);
        }
#pragma unroll
        for (int ni = 0; ni < 16; ++ni)
            oacc[ni] = __builtin_amdgcn_mfma_f32_16x16x32_f16(pa, vf[ni], oacc[ni], 0, 0, 0);

        // ---- (7) full drain: K staging complete, ps reusable ----
        __syncthreads();

        vlane  += 32;
        kstage += 32 * CDIM;
    }

    // ---- row-sum reduce: over lr (16 lanes), then over the jq wave-pair ----
#pragma unroll
    for (int m = 1; m <= 8; m <<= 1)
#pragma unroll
        for (int r = 0; r < 4; ++r)
            lsum[r] += __shfl_xor(lsum[r], m, 64);
    if (lr == 0)
#pragma unroll
        for (int r = 0; r < 4; ++r)
            red[w][iq * 16 + lk * 4 + r] = lsum[r];
    __syncthreads();
    if (tid < 64) {
        int rw = (tid >> 4) << 1;
        float lv = red[rw][tid] + red[rw + 1][tid];
        redt[tid] = 1.0f / lv;
        lbuf[jhalf * 8192 + batch * NPIX + i0 + tid] = lv;
    }
    __syncthreads();

    // ---- store normalized per-half partial O (fp16) ----
    _Float16* dsth = (jhalf ? p1 : p0) + (long)batch * NPIX * CDIM;
#pragma unroll
    for (int r = 0; r < 4; ++r) {
        int row = ro * 16 + lk * 4 + r;
        float rv = redt[row];
#pragma unroll
        for (int ni = 0; ni < 16; ++ni) {
            int c = co * 256 + ni * 16 + lr;
            dsth[(long)(i0 + row) * CDIM + c] = (_Float16)(oacc[ni][r] * rv);
        }
    }
}

// ---------------- combine: out = (O0*l0 + O1*l1) / (l0+l1) ----------------
__global__ void combine_kernel(const _Float16* __restrict__ p0, const _Float16* __restrict__ p1,
                               const float* __restrict__ lbuf, _Float16* __restrict__ out) {
    long g = (long)blockIdx.x * 256 + threadIdx.x;
    long base = g * 8;
    int rowg = (int)(g >> 6);                 // b*4096 + n
    float l0 = lbuf[rowg], l1 = lbuf[8192 + rowg];
    float w0 = l0 / (l0 + l1);
    float w1 = 1.0f - w0;
    hv8 a = *(const hv8*)(p0 + base);
    hv8 b = *(const hv8*)(p1 + base);
    hv8 o;
#pragma unroll
    for (int i = 0; i < 8; ++i)
        o[i] = (_Float16)((float)a[i] * w0 + (float)b[i] * w1);
    *(hv8*)(out + base) = o;
}

extern "C" void kernel_launch(void* const* d_in, const int* in_sizes, int n_in,
                              void* d_out, int out_size, void* d_ws, size_t ws_size,
                              hipStream_t stream) {
    const float* x     = (const float*)d_in[0];
    const float* gamma = (const float*)d_in[1];
    const float* beta  = (const float*)d_in[2];
    const float* wq    = (const float*)d_in[3];
    const float* bq    = (const float*)d_in[4];
    const float* wk    = (const float*)d_in[5];
    const float* bk    = (const float*)d_in[6];
    const float* wv    = (const float*)d_in[7];
    const float* bv    = (const float*)d_in[8];
    const float* wo    = (const float*)d_in[9];
    const float* bo    = (const float*)d_in[10];
    float* out = (float*)d_out;

    char* ws = (char*)d_ws;
    float* stats = (float*)ws;
    _Float16* wqb = (_Float16*)(ws + 1024);
    _Float16* wkb = wqb + 262144;
    _Float16* wvb = wkb + 262144;
    _Float16* wob = wvb + 262144;
    _Float16* hT  = wob + 262144;
    const long TSZ = (long)2 * NPIX * CDIM;
    _Float16* qT = hT + TSZ;
    _Float16* kT = qT + TSZ;
    _Float16* vv = kT + TSZ;
    _Float16* oT = vv + TSZ;
    float* lbuf = (float*)(oT + TSZ);        // 2 halves x 8192 rows

    cvt_w<<<dim3(1024), dim3(256), 0, stream>>>(wq, wk, wv, wo, wqb, wkb, wvb, wob);
    stats_kernel<<<dim3(64), dim3(256), 0, stream>>>(x, stats);
    normT_kernel<<<dim3(16, 128, 2), dim3(256), 0, stream>>>(x, stats, gamma, beta, hT);

    const long NC = (long)NPIX * CDIM;
    gemm_bt_kernel<0><<<dim3(4, 32, 2), dim3(256), 0, stream>>>(
        hT, wqb, (void*)qT, bq, nullptr, NPIX, CDIM, CDIM, NC, 0L, NC, 0L);
    gemm_bt_kernel<0><<<dim3(4, 32, 2), dim3(256), 0, stream>>>(
        hT, wkb, (void*)kT, bk, nullptr, NPIX, CDIM, CDIM, NC, 0L, NC, 0L);
    gemm_bt_kernel<1><<<dim3(32, 4, 2), dim3(256), 0, stream>>>(
        wvb, hT, (void*)vv, bv, nullptr, CDIM, NPIX, CDIM, 0L, NC, NC, 0L);

    // attention: partial jhalf0 -> oT, jhalf1 -> hT (dead), sums -> lbuf
    attn_kernel<<<dim3(256), dim3(512), 0, stream>>>(qT, kT, vv, oT, hT, lbuf);

    // combine halves into qT (dead after attn)
    combine_kernel<<<dim3(2048), dim3(256), 0, stream>>>(oT, hT, lbuf, qT);

    gemm_bt_kernel<2><<<dim3(32, 4, 2), dim3(256), 0, stream>>>(
        wob, qT, (void*)out, bo, x, CDIM, NPIX, CDIM, 0L, NC, NC, NC);
}

// Round 5
// 226.846 us; speedup vs baseline: 1.6992x; 1.6992x over previous
//
#include <hip/hip_runtime.h>
#include <stdint.h>

#define NPIX 4096
#define CDIM 512

typedef _Float16 hv8 __attribute__((ext_vector_type(8)));
typedef float f32x4 __attribute__((ext_vector_type(4)));

__device__ __forceinline__ void lds_direct16(const _Float16* g, _Float16* l) {
    __builtin_amdgcn_global_load_lds(
        (const __attribute__((address_space(1))) void*)g,
        (__attribute__((address_space(3))) void*)l, 16, 0, 0);
}

// ---------------- weight fp32 -> fp16 ----------------
__global__ void cvt_w(const float* __restrict__ s0, const float* __restrict__ s1,
                      const float* __restrict__ s2, const float* __restrict__ s3,
                      _Float16* __restrict__ d0, _Float16* __restrict__ d1,
                      _Float16* __restrict__ d2, _Float16* __restrict__ d3) {
    int i = blockIdx.x * 256 + threadIdx.x;
    d0[i] = (_Float16)s0[i];
    d1[i] = (_Float16)s1[i];
    d2[i] = (_Float16)s2[i];
    d3[i] = (_Float16)s3[i];
}

// ---------------- groupnorm stats: one block per (b,g) ----------------
__global__ void stats_kernel(const float* __restrict__ x, float* __restrict__ stats) {
    int idx = blockIdx.x;
    const float4* base = (const float4*)(x + (long)idx * 16 * NPIX);
    int tid = threadIdx.x;
    float s = 0.f, sq = 0.f;
    for (int it = 0; it < 64; ++it) {
        float4 f = base[it * 256 + tid];
        s  += f.x + f.y + f.z + f.w;
        sq += f.x * f.x + f.y * f.y + f.z * f.z + f.w * f.w;
    }
    __shared__ float rs[256], rq[256];
    rs[tid] = s; rq[tid] = sq;
    __syncthreads();
    for (int st = 128; st > 0; st >>= 1) {
        if (tid < st) { rs[tid] += rs[tid + st]; rq[tid] += rq[tid + st]; }
        __syncthreads();
    }
    if (tid == 0) {
        float mean = rs[0] * (1.0f / 65536.0f);
        float var  = rq[0] * (1.0f / 65536.0f) - mean * mean;
        stats[idx * 2]     = mean;
        stats[idx * 2 + 1] = rsqrtf(var + 1e-6f);
    }
}

// ---------------- normalize + transpose: hT[b][n][c] = GN(x)[b][c][n] ----------------
__global__ void normT_kernel(const float* __restrict__ x, const float* __restrict__ stats,
                             const float* __restrict__ gamma, const float* __restrict__ beta,
                             _Float16* __restrict__ hT) {
    int b = blockIdx.z, c0 = blockIdx.x * 32, n0 = blockIdx.y * 32;
    int tid = threadIdx.x;
    __shared__ float t[32][33];
    int cl = tid >> 5;
    int nl = tid & 31;
    for (int r = 0; r < 4; ++r)
        t[r * 8 + cl][nl] = x[(long)b * CDIM * NPIX + (long)(c0 + r * 8 + cl) * NPIX + n0 + nl];
    __syncthreads();
    for (int r = 0; r < 4; ++r) {
        int nr = r * 8 + cl;
        int c = c0 + nl;
        float m    = stats[(b * 32 + (c >> 4)) * 2];
        float rstd = stats[(b * 32 + (c >> 4)) * 2 + 1];
        float val = (t[nl][nr] - m) * rstd * gamma[c] + beta[c];
        hT[(long)b * NPIX * CDIM + (long)(n0 + nr) * CDIM + c] = (_Float16)val;
    }
}

// ---------------- bt-form GEMM: D[M][N] = A[M][K] * BT[N][K]^T ----------------
template<int EPI>
__launch_bounds__(256, 2)
__global__ void gemm_bt_kernel(const _Float16* __restrict__ A, const _Float16* __restrict__ BT,
                               void* __restrict__ D, const float* __restrict__ bias,
                               const float* __restrict__ resid,
                               int M, int N, int K,
                               long aBatch, long bBatch, long dBatch, long rBatch) {
    const int b = blockIdx.z;
    A  += (long)b * aBatch;
    BT += (long)b * bBatch;
    const int m0 = blockIdx.y * 128;
    const int n0 = blockIdx.x * 128;
    const int tid = threadIdx.x;
    const int l = tid & 63;
    const int w = tid >> 6;
    const int wm = (w >> 1) * 64;
    const int wn = (w & 1) * 64;
    const int lr = l & 15;
    const int lk = l >> 4;
    __shared__ __align__(16) _Float16 As[128 * 32];
    __shared__ __align__(16) _Float16 Bs[128 * 32];
    f32x4 acc[4][4] = {};
    const int nK = K >> 5;
    for (int kt = 0; kt < nK; ++kt) {
        const int kb = kt * 32;
#pragma unroll
        for (int c = 0; c < 2; ++c) {
            int chunk = c * 256 + tid;
            int row = chunk >> 2;
            int k8 = (chunk & 3) * 8;
            _Float16* ldsA = As + (size_t)(c * 256 + (tid & ~63)) * 8;
            _Float16* ldsB = Bs + (size_t)(c * 256 + (tid & ~63)) * 8;
            lds_direct16(A  + (long)(m0 + row) * K + kb + k8, ldsA);
            lds_direct16(BT + (long)(n0 + row) * K + kb + k8, ldsB);
        }
        __syncthreads();
        hv8 af[4], bfr[4];
#pragma unroll
        for (int mi = 0; mi < 4; ++mi)
            af[mi] = *(const hv8*)(As + (size_t)(wm + mi * 16 + lr) * 32 + lk * 8);
#pragma unroll
        for (int ni = 0; ni < 4; ++ni)
            bfr[ni] = *(const hv8*)(Bs + (size_t)(wn + ni * 16 + lr) * 32 + lk * 8);
#pragma unroll
        for (int mi = 0; mi < 4; ++mi)
#pragma unroll
            for (int ni = 0; ni < 4; ++ni)
                acc[mi][ni] = __builtin_amdgcn_mfma_f32_16x16x32_f16(af[mi], bfr[ni], acc[mi][ni], 0, 0, 0);
        __syncthreads();
    }
#pragma unroll
    for (int mi = 0; mi < 4; ++mi)
#pragma unroll
        for (int ni = 0; ni < 4; ++ni)
#pragma unroll
            for (int r = 0; r < 4; ++r) {
                int row = m0 + wm + mi * 16 + lk * 4 + r;
                int col = n0 + wn + ni * 16 + lr;
                float val = acc[mi][ni][r];
                if (EPI == 0) {
                    ((_Float16*)D)[(long)b * dBatch + (long)row * N + col] = (_Float16)(val + bias[col]);
                } else if (EPI == 1) {
                    ((_Float16*)D)[(long)b * dBatch + (long)row * N + col] = (_Float16)(val + bias[row]);
                } else {
                    long idx = (long)row * N + col;
                    ((float*)D)[(long)b * dBatch + idx] =
                        val + bias[row] + resid[(long)b * rBatch + idx];
                }
            }
}

// ---------------- flash attention v5: i-tile 64, j-tile 64, j-split 2 ----------------
// Grid 256 linear; decode pins each (batch,jhalf) to an XCD pair so its K/V half
// (2+2 MB) is L2-resident. QK: wave (iq=w>>1, jq=w&1) computes S rows iq*16,
// cols jq*32..+63 (two 16x16 tiles). PV: wave owns c-range w*64 (UNIQUE -> no
// V duplication), all 64 i-rows, P read from shared LDS tile.
__launch_bounds__(512, 2)
__global__ void attn_kernel(const _Float16* __restrict__ qT, const _Float16* __restrict__ kT,
                            const _Float16* __restrict__ v,
                            _Float16* __restrict__ p0, _Float16* __restrict__ p1,
                            float* __restrict__ lbuf) {
    __shared__ __align__(16) _Float16 Ks[2][64 * 512];   // 128 KB, XOR-swizzled rows
    __shared__ __align__(16) _Float16 ps[64 * 64];       // 8 KB, XOR-swizzled (128B rows)
    __shared__ float red[8][64];
    __shared__ float redt[64];

    const int g = blockIdx.x;
    const int xcd = g & 7;
    const int comb = xcd >> 1;                  // 0..3 -> (batch, jhalf)
    const int itile = ((g >> 3) << 1) | (xcd & 1);   // 0..63
    const int batch = comb >> 1;
    const int jhalf = comb & 1;
    const int i0 = itile * 64;
    const int jbase = jhalf * 2048;

    const int tid = threadIdx.x;
    const int l = tid & 63, w = tid >> 6;
    const int lr = l & 15, lk = l >> 4;
    const int iq = w >> 1, jq = w & 1;          // QK quadrant

    const _Float16* qb = qT + (long)batch * NPIX * CDIM;
    const _Float16* kb = kT + (long)batch * NPIX * CDIM;
    const _Float16* vb = v  + (long)batch * CDIM * NPIX;

    // Q fragments: rows i0 + iq*16 + lr, 16 k-chunks (64 VGPR)
    hv8 af[16];
    {
        const _Float16* qr = qb + (long)(i0 + iq * 16 + lr) * CDIM + lk * 8;
#pragma unroll
        for (int kk = 0; kk < 16; ++kk)
            af[kk] = *(const hv8*)(qr + kk * 32);
    }

    f32x4 oacc[4][4] = {};   // rows mi*16+lk*4+r, cols w*64+ni*16+lr (64 VGPR)
    float lsum[4] = {};
    hv8 vf[4][2];

    // prologue: stage K tile 0 (rows w*8+q)
    {
        const _Float16* kp = kb + (long)(jbase + w * 8) * CDIM;
#pragma unroll
        for (int q = 0; q < 8; ++q) {
            int cc = l ^ q;                      // row&7 == q
            lds_direct16(kp + (long)q * CDIM + cc * 8, &Ks[0][(w * 8 + q) * 512]);
        }
    }
    __syncthreads();

    const float scale = 0.044194173824159216f;   // 1/sqrt(512)
    const _Float16* vlane  = vb + (long)(w * 64 + lr) * NPIX + jbase + lk * 8;
    const _Float16* kstage = kb + (long)(jbase + 64 + w * 8) * CDIM;

    for (int jt = 0; jt < 32; ++jt) {
        const _Float16* kcur = Ks[jt & 1];
        _Float16* knxt = Ks[(jt + 1) & 1];

        // ---- (1) V fragments for THIS step (issued first; unique c-range per wave) ----
#pragma unroll
        for (int ni = 0; ni < 4; ++ni)
#pragma unroll
            for (int jh = 0; jh < 2; ++jh)
                vf[ni][jh] = *(const hv8*)(vlane + (long)ni * (16 * NPIX) + jh * 32);
        __builtin_amdgcn_sched_barrier(0);

        // ---- (2) K staging for NEXT step (stays in flight past mid-barrier) ----
        if (jt < 31) {
#pragma unroll
            for (int q = 0; q < 8; ++q) {
                int cc = l ^ q;
                lds_direct16(kstage + (long)q * CDIM + cc * 8, &knxt[(w * 8 + q) * 512]);
            }
        }
        __builtin_amdgcn_sched_barrier(0);

        // ---- (3) QK: two 16x16 tiles (rows iq*16, cols jq*32 and jq*32+16) ----
        f32x4 s0 = {}, s1 = {};
        {
            const char* kbase = (const char*)kcur;
            const int j0c = jq * 32 + lr;
            const int j1c = j0c + 16;
            const uint32_t sw0 = (uint32_t)((j0c & 7) << 4);
            const uint32_t sw1 = (uint32_t)((j1c & 7) << 4);
#pragma unroll
            for (int kk = 0; kk < 16; ++kk) {
                hv8 bf0 = *(const hv8*)(kbase + (((uint32_t)(j0c * 1024 + kk * 64 + lk * 16)) ^ sw0));
                s0 = __builtin_amdgcn_mfma_f32_16x16x32_f16(af[kk], bf0, s0, 0, 0, 0);
                hv8 bf1 = *(const hv8*)(kbase + (((uint32_t)(j1c * 1024 + kk * 64 + lk * 16)) ^ sw1));
                s1 = __builtin_amdgcn_mfma_f32_16x16x32_f16(af[kk], bf1, s1, 0, 0, 0);
            }
        }

        // ---- (4) exp + ps write (swizzled, 128B rows) ----
#pragma unroll
        for (int r = 0; r < 4; ++r) {
            int i = iq * 16 + lk * 4 + r;
            uint32_t sw = (uint32_t)((i & 7) << 4);
            float pe0 = __expf(s0[r] * scale);
            float pe1 = __expf(s1[r] * scale);
            lsum[r] += pe0 + pe1;
            int j0c = jq * 32 + lr;
            *(_Float16*)((char*)ps + (((uint32_t)(i * 128 + j0c * 2)) ^ sw)) = (_Float16)pe0;
            *(_Float16*)((char*)ps + (((uint32_t)(i * 128 + (j0c + 16) * 2)) ^ sw)) = (_Float16)pe1;
        }

        // ---- (5) mid barrier: drain LDS only; K staging stays outstanding ----
        asm volatile("s_waitcnt lgkmcnt(0)" ::: "memory");
        __builtin_amdgcn_sched_barrier(0);
        __builtin_amdgcn_s_barrier();

        // ---- (6) PV: all 64 P-rows x wave's 64 c-cols ----
#pragma unroll
        for (int mi = 0; mi < 4; ++mi)
#pragma unroll
            for (int jh = 0; jh < 2; ++jh) {
                int row = mi * 16 + lr;
                uint32_t off = ((uint32_t)(row * 128 + jh * 64 + lk * 16)) ^ ((uint32_t)((row & 7) << 4));
                hv8 pa = *(const hv8*)((const char*)ps + off);
#pragma unroll
                for (int ni = 0; ni < 4; ++ni)
                    oacc[mi][ni] = __builtin_amdgcn_mfma_f32_16x16x32_f16(pa, vf[ni][jh], oacc[mi][ni], 0, 0, 0);
            }

        // ---- (7) full drain: K staging complete, ps reusable ----
        __syncthreads();

        vlane  += 64;
        kstage += 64 * CDIM;
    }

    // ---- row-sum reduce: over lr (16 lanes), then over the jq wave-pair ----
#pragma unroll
    for (int m = 1; m <= 8; m <<= 1)
#pragma unroll
        for (int r = 0; r < 4; ++r)
            lsum[r] += __shfl_xor(lsum[r], m, 64);
    if (lr == 0)
#pragma unroll
        for (int r = 0; r < 4; ++r)
            red[w][iq * 16 + lk * 4 + r] = lsum[r];
    __syncthreads();
    if (tid < 64) {
        int iq2 = tid >> 4;
        float lv = red[iq2 * 2][tid] + red[iq2 * 2 + 1][tid];
        redt[tid] = 1.0f / lv;
        lbuf[jhalf * 8192 + batch * NPIX + i0 + tid] = lv;
    }
    __syncthreads();

    // ---- store normalized per-half partial O (fp16) ----
    _Float16* dsth = (jhalf ? p1 : p0) + (long)batch * NPIX * CDIM;
#pragma unroll
    for (int mi = 0; mi < 4; ++mi)
#pragma unroll
        for (int r = 0; r < 4; ++r) {
            int row = mi * 16 + lk * 4 + r;
            float rv = redt[row];
#pragma unroll
            for (int ni = 0; ni < 4; ++ni) {
                int c = w * 64 + ni * 16 + lr;
                dsth[(long)(i0 + row) * CDIM + c] = (_Float16)(oacc[mi][ni][r] * rv);
            }
        }
}

// ---------------- combine: out = (O0*l0 + O1*l1) / (l0+l1) ----------------
__global__ void combine_kernel(const _Float16* __restrict__ p0, const _Float16* __restrict__ p1,
                               const float* __restrict__ lbuf, _Float16* __restrict__ out) {
    long g = (long)blockIdx.x * 256 + threadIdx.x;
    long base = g * 8;
    int rowg = (int)(g >> 6);                 // b*4096 + n
    float l0 = lbuf[rowg], l1 = lbuf[8192 + rowg];
    float w0 = l0 / (l0 + l1);
    float w1 = 1.0f - w0;
    hv8 a = *(const hv8*)(p0 + base);
    hv8 b = *(const hv8*)(p1 + base);
    hv8 o;
#pragma unroll
    for (int i = 0; i < 8; ++i)
        o[i] = (_Float16)((float)a[i] * w0 + (float)b[i] * w1);
    *(hv8*)(out + base) = o;
}

extern "C" void kernel_launch(void* const* d_in, const int* in_sizes, int n_in,
                              void* d_out, int out_size, void* d_ws, size_t ws_size,
                              hipStream_t stream) {
    const float* x     = (const float*)d_in[0];
    const float* gamma = (const float*)d_in[1];
    const float* beta  = (const float*)d_in[2];
    const float* wq    = (const float*)d_in[3];
    const float* bq    = (const float*)d_in[4];
    const float* wk    = (const float*)d_in[5];
    const float* bk    = (const float*)d_in[6];
    const float* wv    = (const float*)d_in[7];
    const float* bv    = (const float*)d_in[8];
    const float* wo    = (const float*)d_in[9];
    const float* bo    = (const float*)d_in[10];
    float* out = (float*)d_out;

    char* ws = (char*)d_ws;
    float* stats = (float*)ws;
    _Float16* wqb = (_Float16*)(ws + 1024);
    _Float16* wkb = wqb + 262144;
    _Float16* wvb = wkb + 262144;
    _Float16* wob = wvb + 262144;
    _Float16* hT  = wob + 262144;
    const long TSZ = (long)2 * NPIX * CDIM;
    _Float16* qT = hT + TSZ;
    _Float16* kT = qT + TSZ;
    _Float16* vv = kT + TSZ;
    _Float16* oT = vv + TSZ;
    float* lbuf = (float*)(oT + TSZ);        // 2 halves x 8192 rows

    cvt_w<<<dim3(1024), dim3(256), 0, stream>>>(wq, wk, wv, wo, wqb, wkb, wvb, wob);
    stats_kernel<<<dim3(64), dim3(256), 0, stream>>>(x, stats);
    normT_kernel<<<dim3(16, 128, 2), dim3(256), 0, stream>>>(x, stats, gamma, beta, hT);

    const long NC = (long)NPIX * CDIM;
    gemm_bt_kernel<0><<<dim3(4, 32, 2), dim3(256), 0, stream>>>(
        hT, wqb, (void*)qT, bq, nullptr, NPIX, CDIM, CDIM, NC, 0L, NC, 0L);
    gemm_bt_kernel<0><<<dim3(4, 32, 2), dim3(256), 0, stream>>>(
        hT, wkb, (void*)kT, bk, nullptr, NPIX, CDIM, CDIM, NC, 0L, NC, 0L);
    gemm_bt_kernel<1><<<dim3(32, 4, 2), dim3(256), 0, stream>>>(
        wvb, hT, (void*)vv, bv, nullptr, CDIM, NPIX, CDIM, 0L, NC, NC, 0L);

    // attention: partial jhalf0 -> oT, jhalf1 -> hT (dead), sums -> lbuf
    attn_kernel<<<dim3(256), dim3(512), 0, stream>>>(qT, kT, vv, oT, hT, lbuf);

    // combine halves into qT (dead after attn)
    combine_kernel<<<dim3(2048), dim3(256), 0, stream>>>(oT, hT, lbuf, qT);

    gemm_bt_kernel<2><<<dim3(32, 4, 2), dim3(256), 0, stream>>>(
        wob, qT, (void*)out, bo, x, CDIM, NPIX, CDIM, 0L, NC, NC, NC);
}

// Round 6
// 206.164 us; speedup vs baseline: 1.8697x; 1.1003x over previous
//
#include <hip/hip_runtime.h>
#include <stdint.h>

#define NPIX 4096
#define CDIM 512

typedef _Float16 hv8 __attribute__((ext_vector_type(8)));
typedef float f32x4 __attribute__((ext_vector_type(4)));

__device__ __forceinline__ void lds_direct16(const _Float16* g, _Float16* l) {
    __builtin_amdgcn_global_load_lds(
        (const __attribute__((address_space(1))) void*)g,
        (__attribute__((address_space(3))) void*)l, 16, 0, 0);
}

// ---------------- weight fp32 -> fp16 ----------------
__global__ void cvt_w(const float* __restrict__ s0, const float* __restrict__ s1,
                      const float* __restrict__ s2, const float* __restrict__ s3,
                      _Float16* __restrict__ d0, _Float16* __restrict__ d1,
                      _Float16* __restrict__ d2, _Float16* __restrict__ d3) {
    int i = blockIdx.x * 256 + threadIdx.x;
    d0[i] = (_Float16)s0[i];
    d1[i] = (_Float16)s1[i];
    d2[i] = (_Float16)s2[i];
    d3[i] = (_Float16)s3[i];
}

// ---------------- groupnorm stats: one block per (b,g) ----------------
__global__ void stats_kernel(const float* __restrict__ x, float* __restrict__ stats) {
    int idx = blockIdx.x;
    const float4* base = (const float4*)(x + (long)idx * 16 * NPIX);
    int tid = threadIdx.x;
    float s = 0.f, sq = 0.f;
    for (int it = 0; it < 64; ++it) {
        float4 f = base[it * 256 + tid];
        s  += f.x + f.y + f.z + f.w;
        sq += f.x * f.x + f.y * f.y + f.z * f.z + f.w * f.w;
    }
    __shared__ float rs[256], rq[256];
    rs[tid] = s; rq[tid] = sq;
    __syncthreads();
    for (int st = 128; st > 0; st >>= 1) {
        if (tid < st) { rs[tid] += rs[tid + st]; rq[tid] += rq[tid + st]; }
        __syncthreads();
    }
    if (tid == 0) {
        float mean = rs[0] * (1.0f / 65536.0f);
        float var  = rq[0] * (1.0f / 65536.0f) - mean * mean;
        stats[idx * 2]     = mean;
        stats[idx * 2 + 1] = rsqrtf(var + 1e-6f);
    }
}

// ---------------- normalize + transpose: hT[b][n][c] = GN(x)[b][c][n] ----------------
__global__ void normT_kernel(const float* __restrict__ x, const float* __restrict__ stats,
                             const float* __restrict__ gamma, const float* __restrict__ beta,
                             _Float16* __restrict__ hT) {
    int b = blockIdx.z, c0 = blockIdx.x * 32, n0 = blockIdx.y * 32;
    int tid = threadIdx.x;
    __shared__ float t[32][33];
    int cl = tid >> 5;
    int nl = tid & 31;
    for (int r = 0; r < 4; ++r)
        t[r * 8 + cl][nl] = x[(long)b * CDIM * NPIX + (long)(c0 + r * 8 + cl) * NPIX + n0 + nl];
    __syncthreads();
    for (int r = 0; r < 4; ++r) {
        int nr = r * 8 + cl;
        int c = c0 + nl;
        float m    = stats[(b * 32 + (c >> 4)) * 2];
        float rstd = stats[(b * 32 + (c >> 4)) * 2 + 1];
        float val = (t[nl][nr] - m) * rstd * gamma[c] + beta[c];
        hT[(long)b * NPIX * CDIM + (long)(n0 + nr) * CDIM + c] = (_Float16)val;
    }
}

// ---------------- bt-form GEMM: D[M][N] = A[M][K] * BT[N][K]^T ----------------
template<int EPI>
__launch_bounds__(256, 2)
__global__ void gemm_bt_kernel(const _Float16* __restrict__ A, const _Float16* __restrict__ BT,
                               void* __restrict__ D, const float* __restrict__ bias,
                               const float* __restrict__ resid,
                               int M, int N, int K,
                               long aBatch, long bBatch, long dBatch, long rBatch) {
    const int b = blockIdx.z;
    A  += (long)b * aBatch;
    BT += (long)b * bBatch;
    const int m0 = blockIdx.y * 128;
    const int n0 = blockIdx.x * 128;
    const int tid = threadIdx.x;
    const int l = tid & 63;
    const int w = tid >> 6;
    const int wm = (w >> 1) * 64;
    const int wn = (w & 1) * 64;
    const int lr = l & 15;
    const int lk = l >> 4;
    __shared__ __align__(16) _Float16 As[128 * 32];
    __shared__ __align__(16) _Float16 Bs[128 * 32];
    f32x4 acc[4][4] = {};
    const int nK = K >> 5;
    for (int kt = 0; kt < nK; ++kt) {
        const int kb = kt * 32;
#pragma unroll
        for (int c = 0; c < 2; ++c) {
            int chunk = c * 256 + tid;
            int row = chunk >> 2;
            int k8 = (chunk & 3) * 8;
            _Float16* ldsA = As + (size_t)(c * 256 + (tid & ~63)) * 8;
            _Float16* ldsB = Bs + (size_t)(c * 256 + (tid & ~63)) * 8;
            lds_direct16(A  + (long)(m0 + row) * K + kb + k8, ldsA);
            lds_direct16(BT + (long)(n0 + row) * K + kb + k8, ldsB);
        }
        __syncthreads();
        hv8 af[4], bfr[4];
#pragma unroll
        for (int mi = 0; mi < 4; ++mi)
            af[mi] = *(const hv8*)(As + (size_t)(wm + mi * 16 + lr) * 32 + lk * 8);
#pragma unroll
        for (int ni = 0; ni < 4; ++ni)
            bfr[ni] = *(const hv8*)(Bs + (size_t)(wn + ni * 16 + lr) * 32 + lk * 8);
#pragma unroll
        for (int mi = 0; mi < 4; ++mi)
#pragma unroll
            for (int ni = 0; ni < 4; ++ni)
                acc[mi][ni] = __builtin_amdgcn_mfma_f32_16x16x32_f16(af[mi], bfr[ni], acc[mi][ni], 0, 0, 0);
        __syncthreads();
    }
#pragma unroll
    for (int mi = 0; mi < 4; ++mi)
#pragma unroll
        for (int ni = 0; ni < 4; ++ni)
#pragma unroll
            for (int r = 0; r < 4; ++r) {
                int row = m0 + wm + mi * 16 + lk * 4 + r;
                int col = n0 + wn + ni * 16 + lr;
                float val = acc[mi][ni][r];
                if (EPI == 0) {
                    ((_Float16*)D)[(long)b * dBatch + (long)row * N + col] = (_Float16)(val + bias[col]);
                } else if (EPI == 1) {
                    ((_Float16*)D)[(long)b * dBatch + (long)row * N + col] = (_Float16)(val + bias[row]);
                } else {
                    long idx = (long)row * N + col;
                    ((float*)D)[(long)b * dBatch + idx] =
                        val + bias[row] + resid[(long)b * rBatch + idx];
                }
            }
}

// ---------------- flash attention v6: i-tile 64, j-tile 32, j-split 2 ----------------
// Grid 256; XCD pinning as v5 (each (batch,jhalf) owns an XCD pair; K/V half
// L2-resident). BOTH K and V double-buffered in LDS via global_load_lds with
// source-side XOR swizzles; staging for jt+1 issued at top of step jt ->
// full-step latency window. Q frags in registers. PV has no VMEM dependence.
__launch_bounds__(512, 2)
__global__ void attn_kernel(const _Float16* __restrict__ qT, const _Float16* __restrict__ kT,
                            const _Float16* __restrict__ v,
                            _Float16* __restrict__ p0, _Float16* __restrict__ p1,
                            float* __restrict__ lbuf) {
    __shared__ __align__(16) _Float16 Ks[2][32 * 512];   // 2 x 32 KB, rows 1 KB, XOR (j&7)<<4
    __shared__ __align__(16) _Float16 Vs[2][512 * 32];   // 2 x 32 KB, rows 64 B, XOR (c&3)<<4
    __shared__ __align__(16) _Float16 ps[64 * 32];       // 4 KB, rows 64 B, XOR (i&3)<<4
    __shared__ float red[8][64];
    __shared__ float redt[64];

    const int g = blockIdx.x;
    const int xcd = g & 7;
    const int comb = xcd >> 1;                       // (batch, jhalf)
    const int itile = ((g >> 3) << 1) | (xcd & 1);   // 0..63
    const int batch = comb >> 1;
    const int jhalf = comb & 1;
    const int i0 = itile * 64;
    const int jbase = jhalf * 2048;

    const int tid = threadIdx.x;
    const int l = tid & 63, w = tid >> 6;
    const int lr = l & 15, lk = l >> 4;
    const int iq = w >> 1, jq = w & 1;               // QK: rows iq*16, cols jq*16

    const _Float16* qb = qT + (long)batch * NPIX * CDIM;
    const _Float16* kb = kT + (long)batch * NPIX * CDIM;
    const _Float16* vb = v  + (long)batch * CDIM * NPIX;

    // Q fragments: rows i0 + iq*16 + lr, all 16 k-chunks (64 VGPR)
    hv8 af[16];
    {
        const _Float16* qr = qb + (long)(i0 + iq * 16 + lr) * CDIM + lk * 8;
#pragma unroll
        for (int kk = 0; kk < 16; ++kk)
            af[kk] = *(const hv8*)(qr + kk * 32);
    }

    f32x4 oacc[4][4] = {};   // rows mi*16+lk*4+r, cols w*64+ni*16+lr
    float lsum[4] = {};

    // staging: K rows (q*8+w), source col pre-swizzled; V 16 c-rows per instr
    const int vrow_lo = l >> 2;                  // c-row within 16-row group
    const int vslot   = (l & 3) ^ (vrow_lo & 3); // source slot (inverse swizzle)

#define STAGE_TILE(buf, JJ)                                                          \
    {                                                                                \
        const long j0s = (JJ);                                                       \
        _Float16* kd = Ks[buf]; _Float16* vd = Vs[buf];                              \
        _Pragma("unroll")                                                            \
        for (int q = 0; q < 4; ++q) {                                                \
            int row = q * 8 + w;                                                     \
            int cc = l ^ (row & 7);                                                  \
            lds_direct16(kb + (j0s + row) * CDIM + cc * 8, kd + row * 512);          \
        }                                                                            \
        _Pragma("unroll")                                                            \
        for (int q = 0; q < 4; ++q) {                                                \
            int r16 = q * 8 + w;                                                     \
            int crow = r16 * 16 + vrow_lo;                                           \
            lds_direct16(vb + (long)crow * NPIX + j0s + vslot * 8, vd + r16 * 512);  \
        }                                                                            \
    }

    // prologue: stage tile 0
    STAGE_TILE(0, (long)jbase)
    __syncthreads();

    const float scale = 0.044194173824159216f;   // 1/sqrt(512)

    for (int jt = 0; jt < 64; ++jt) {
        const int cur = jt & 1;

        // ---- (1) staging for NEXT step (longest possible window) ----
        if (jt < 63)
            STAGE_TILE(cur ^ 1, (long)jbase + (jt + 1) * 32)
        __builtin_amdgcn_sched_barrier(0);

        // ---- (2) V fragments for THIS step from LDS (ready since last barrier) ----
        hv8 vf[4];
#pragma unroll
        for (int ni = 0; ni < 4; ++ni) {
            int c = w * 64 + ni * 16 + lr;
            uint32_t off = (uint32_t)(c * 64) + (((uint32_t)(lk * 16)) ^ ((uint32_t)((c & 3) << 4)));
            vf[ni] = *(const hv8*)((const char*)Vs[cur] + off);
        }

        // ---- (3) QK: 16x16 tile (rows iq*16, cols jq*16) ----
        f32x4 s = {};
        {
            const char* kbase = (const char*)Ks[cur];
            const int j = jq * 16 + lr;
            const uint32_t sw = (uint32_t)((j & 7) << 4);
#pragma unroll
            for (int kk = 0; kk < 16; ++kk) {
                hv8 bf = *(const hv8*)(kbase + (((uint32_t)(j * 1024 + kk * 64 + lk * 16)) ^ sw));
                s = __builtin_amdgcn_mfma_f32_16x16x32_f16(af[kk], bf, s, 0, 0, 0);
            }
        }

        // ---- (4) exp + ps write (swizzled, 64B rows) ----
#pragma unroll
        for (int r = 0; r < 4; ++r) {
            float p = __expf(s[r] * scale);
            lsum[r] += p;
            int i = iq * 16 + lk * 4 + r;
            int j2 = jq * 16 + lr;
            uint32_t off = (uint32_t)(i * 64) + (((uint32_t)(j2 * 2)) ^ ((uint32_t)((i & 3) << 4)));
            *(_Float16*)((char*)ps + off) = (_Float16)p;
        }

        // ---- (5) mid barrier: LDS drain only; staging stays in flight ----
        asm volatile("s_waitcnt lgkmcnt(0)" ::: "memory");
        __builtin_amdgcn_sched_barrier(0);
        __builtin_amdgcn_s_barrier();
        __builtin_amdgcn_sched_barrier(0);

        // ---- (6) PV: all 64 P-rows x wave's 64 c-cols ----
#pragma unroll
        for (int mi = 0; mi < 4; ++mi) {
            int i2 = mi * 16 + lr;
            uint32_t off = (uint32_t)(i2 * 64) + (((uint32_t)(lk * 16)) ^ ((uint32_t)((i2 & 3) << 4)));
            hv8 pa = *(const hv8*)((const char*)ps + off);
#pragma unroll
            for (int ni = 0; ni < 4; ++ni)
                oacc[mi][ni] = __builtin_amdgcn_mfma_f32_16x16x32_f16(pa, vf[ni], oacc[mi][ni], 0, 0, 0);
        }

        // ---- (7) end barrier: drains staging (full-step window), ps reusable ----
        __syncthreads();
    }

    // ---- row-sum reduce: over lr (16 lanes), then over the jq wave-pair ----
#pragma unroll
    for (int m = 1; m <= 8; m <<= 1)
#pragma unroll
        for (int r = 0; r < 4; ++r)
            lsum[r] += __shfl_xor(lsum[r], m, 64);
    if (lr == 0)
#pragma unroll
        for (int r = 0; r < 4; ++r)
            red[w][iq * 16 + lk * 4 + r] = lsum[r];
    __syncthreads();
    if (tid < 64) {
        int iq2 = tid >> 4;
        float lv = red[iq2 * 2][tid] + red[iq2 * 2 + 1][tid];
        redt[tid] = 1.0f / lv;
        lbuf[jhalf * 8192 + batch * NPIX + i0 + tid] = lv;
    }
    __syncthreads();

    // ---- store normalized per-half partial O (fp16) ----
    _Float16* dsth = (jhalf ? p1 : p0) + (long)batch * NPIX * CDIM;
#pragma unroll
    for (int mi = 0; mi < 4; ++mi)
#pragma unroll
        for (int r = 0; r < 4; ++r) {
            int row = mi * 16 + lk * 4 + r;
            float rv = redt[row];
#pragma unroll
            for (int ni = 0; ni < 4; ++ni) {
                int c = w * 64 + ni * 16 + lr;
                dsth[(long)(i0 + row) * CDIM + c] = (_Float16)(oacc[mi][ni][r] * rv);
            }
        }
#undef STAGE_TILE
}

// ---------------- combine: out = (O0*l0 + O1*l1) / (l0+l1) ----------------
__global__ void combine_kernel(const _Float16* __restrict__ p0, const _Float16* __restrict__ p1,
                               const float* __restrict__ lbuf, _Float16* __restrict__ out) {
    long g = (long)blockIdx.x * 256 + threadIdx.x;
    long base = g * 8;
    int rowg = (int)(g >> 6);                 // b*4096 + n
    float l0 = lbuf[rowg], l1 = lbuf[8192 + rowg];
    float w0 = l0 / (l0 + l1);
    float w1 = 1.0f - w0;
    hv8 a = *(const hv8*)(p0 + base);
    hv8 b = *(const hv8*)(p1 + base);
    hv8 o;
#pragma unroll
    for (int i = 0; i < 8; ++i)
        o[i] = (_Float16)((float)a[i] * w0 + (float)b[i] * w1);
    *(hv8*)(out + base) = o;
}

extern "C" void kernel_launch(void* const* d_in, const int* in_sizes, int n_in,
                              void* d_out, int out_size, void* d_ws, size_t ws_size,
                              hipStream_t stream) {
    const float* x     = (const float*)d_in[0];
    const float* gamma = (const float*)d_in[1];
    const float* beta  = (const float*)d_in[2];
    const float* wq    = (const float*)d_in[3];
    const float* bq    = (const float*)d_in[4];
    const float* wk    = (const float*)d_in[5];
    const float* bk    = (const float*)d_in[6];
    const float* wv    = (const float*)d_in[7];
    const float* bv    = (const float*)d_in[8];
    const float* wo    = (const float*)d_in[9];
    const float* bo    = (const float*)d_in[10];
    float* out = (float*)d_out;

    char* ws = (char*)d_ws;
    float* stats = (float*)ws;
    _Float16* wqb = (_Float16*)(ws + 1024);
    _Float16* wkb = wqb + 262144;
    _Float16* wvb = wkb + 262144;
    _Float16* wob = wvb + 262144;
    _Float16* hT  = wob + 262144;
    const long TSZ = (long)2 * NPIX * CDIM;
    _Float16* qT = hT + TSZ;
    _Float16* kT = qT + TSZ;
    _Float16* vv = kT + TSZ;
    _Float16* oT = vv + TSZ;
    float* lbuf = (float*)(oT + TSZ);        // 2 halves x 8192 rows

    cvt_w<<<dim3(1024), dim3(256), 0, stream>>>(wq, wk, wv, wo, wqb, wkb, wvb, wob);
    stats_kernel<<<dim3(64), dim3(256), 0, stream>>>(x, stats);
    normT_kernel<<<dim3(16, 128, 2), dim3(256), 0, stream>>>(x, stats, gamma, beta, hT);

    const long NC = (long)NPIX * CDIM;
    gemm_bt_kernel<0><<<dim3(4, 32, 2), dim3(256), 0, stream>>>(
        hT, wqb, (void*)qT, bq, nullptr, NPIX, CDIM, CDIM, NC, 0L, NC, 0L);
    gemm_bt_kernel<0><<<dim3(4, 32, 2), dim3(256), 0, stream>>>(
        hT, wkb, (void*)kT, bk, nullptr, NPIX, CDIM, CDIM, NC, 0L, NC, 0L);
    gemm_bt_kernel<1><<<dim3(32, 4, 2), dim3(256), 0, stream>>>(
        wvb, hT, (void*)vv, bv, nullptr, CDIM, NPIX, CDIM, 0L, NC, NC, 0L);

    // attention: partial jhalf0 -> oT, jhalf1 -> hT (dead), sums -> lbuf
    attn_kernel<<<dim3(256), dim3(512), 0, stream>>>(qT, kT, vv, oT, hT, lbuf);

    // combine halves into qT (dead after attn)
    combine_kernel<<<dim3(2048), dim3(256), 0, stream>>>(oT, hT, lbuf, qT);

    gemm_bt_kernel<2><<<dim3(32, 4, 2), dim3(256), 0, stream>>>(
        wob, qT, (void*)out, bo, x, CDIM, NPIX, CDIM, 0L, NC, NC, NC);
}